// Round 8
// baseline (197.758 us; speedup 1.0000x reference)
//
#include <hip/hip_runtime.h>
#include <hip/hip_bf16.h>
#include <math.h>

#define SEQ 2048
#define DIM 1024
#define NH 16
#define FDIM 16
#define QS 4608   // fused qkv row stride

typedef __bf16 bf16x8 __attribute__((ext_vector_type(8)));
typedef float f32x4 __attribute__((ext_vector_type(4)));
typedef __hip_bfloat16 bf16g;

__device__ __forceinline__ void gld16(const void* g, void* l) {
    __builtin_amdgcn_global_load_lds((const __attribute__((address_space(1))) void*)g,
                                     (__attribute__((address_space(3))) void*)l, 16, 0, 0);
}

// ---- 256-thread stager (GEMM): 128x64 bf16 tile, 16B-chunk XOR swizzle ----
__device__ __forceinline__ void stage128(char* lds, const bf16g* src, int stride, int tid) {
#pragma unroll
    for (int c = 0; c < 4; ++c) {
        const int idx = ((tid >> 6) * 256) + c * 64 + (tid & 63);
        const int row = idx >> 3, gg = idx & 7;
        gld16(src + (size_t)row * stride + ((gg ^ (row & 7)) * 8), lds + idx * 16);
    }
}
__device__ __forceinline__ bf16x8 frag64(const char* lds, int row, int kbase) {
    const int ch = kbase >> 3;
    return *(const bf16x8*)(lds + row * 128 + ((ch ^ (row & 7)) << 4));
}

// ------------------- prep kernels -------------------
__global__ __launch_bounds__(256) void convert_h(const float* __restrict__ in, bf16g* __restrict__ out,
                                                 const int* __restrict__ amask, float* __restrict__ bias) {
    const size_t base = ((size_t)blockIdx.x * 256 + threadIdx.x) * 8;
    float4 a = *(const float4*)(in + base);
    float4 b = *(const float4*)(in + base + 4);
    __attribute__((aligned(16))) bf16g t[8];
    t[0] = __float2bfloat16(a.x); t[1] = __float2bfloat16(a.y);
    t[2] = __float2bfloat16(a.z); t[3] = __float2bfloat16(a.w);
    t[4] = __float2bfloat16(b.x); t[5] = __float2bfloat16(b.y);
    t[6] = __float2bfloat16(b.z); t[7] = __float2bfloat16(b.w);
    *(uint4*)(out + base) = *(const uint4*)t;
    const int tg = blockIdx.x * 256 + threadIdx.x;
    if (tg < SEQ) bias[tg] = (amask[tg] != 0) ? 0.f : -1e30f;
}

// 8 batched weight transposes: f32 [1024][C] -> bf16 [C][os]
struct TP8 { const float* src[8]; bf16g* dst[8]; int C[8]; int os[8]; };
__global__ __launch_bounds__(256) void transpose8(TP8 jp) {
    const int j = blockIdx.z;
    const int C = jp.C[j];
    const int bc = blockIdx.x * 32;
    if (bc >= C) return;
    __shared__ float T[32][33];
    const float* in = jp.src[j];
    bf16g* out = jp.dst[j];
    const int os = jp.os[j];
    const int tid = threadIdx.x;
    const int br = blockIdx.y * 32;
    const int r = tid >> 3, c4 = (tid & 7) * 4;
    float4 v = *(const float4*)(in + (size_t)(br + r) * C + bc + c4);
    T[r][c4 + 0] = v.x; T[r][c4 + 1] = v.y; T[r][c4 + 2] = v.z; T[r][c4 + 3] = v.w;
    __syncthreads();
    const int c = tid >> 3, r4 = (tid & 7) * 4;
    __attribute__((aligned(8))) bf16g o[4];
#pragma unroll
    for (int i = 0; i < 4; ++i) o[i] = __float2bfloat16(T[r4 + i][c]);
    *(ushort4*)(out + (size_t)(bc + c) * os + br + r4) = *(const ushort4*)o;
}

// both V transposes: qkv cols [512..1536) / [3584..4608) -> [1024][2048]
__global__ __launch_bounds__(256) void transposeV(const bf16g* __restrict__ qkv,
                                                  bf16g* __restrict__ vlinT,
                                                  bf16g* __restrict__ vwT) {
    __shared__ unsigned short T[32][33];
    const int z = blockIdx.z;
    const unsigned short* in = (const unsigned short*)(qkv + (z ? 3584 : 512));
    unsigned short* out = (unsigned short*)(z ? vwT : vlinT);
    const int tid = threadIdx.x;
    const int br = blockIdx.y * 32, bc = blockIdx.x * 32;
    const int r = tid >> 3, c4 = (tid & 7) * 4;
    ushort4 v = *(const ushort4*)(in + (size_t)(br + r) * QS + bc + c4);
    T[r][c4 + 0] = v.x; T[r][c4 + 1] = v.y; T[r][c4 + 2] = v.z; T[r][c4 + 3] = v.w;
    __syncthreads();
    const int c = tid >> 3, r4 = (tid & 7) * 4;
    ushort4 o;
    o.x = T[r4 + 0][c]; o.y = T[r4 + 1][c]; o.z = T[r4 + 2][c]; o.w = T[r4 + 3][c];
    *(ushort4*)(out + (size_t)(bc + c) * SEQ + br + r4) = o;
}

// ------------------- bf16 MFMA GEMM, 2-phase pipelined -------------------
template <int MODE>
__global__ __launch_bounds__(256) void gemm_bf16(const bf16g* __restrict__ A,
                                                 const bf16g* __restrict__ BT,
                                                 float* __restrict__ Cf, bf16g* __restrict__ Cb,
                                                 int M, int N, int K) {
    __shared__ char As[2][16384];
    __shared__ char Bs[2][16384];
    const int tid = threadIdx.x, lane = tid & 63, w = tid >> 6;
    const int wr = (w >> 1) * 64, wc = (w & 1) * 64;
    const int bm = blockIdx.y * 128, bn = blockIdx.x * 128;
    const int l15 = lane & 15, l4 = lane >> 4;
    f32x4 z = {0.f, 0.f, 0.f, 0.f};
    f32x4 acc[4][4];
#pragma unroll
    for (int m = 0; m < 4; ++m)
#pragma unroll
        for (int n = 0; n < 4; ++n) acc[m][n] = z;

    stage128(As[0], A + (size_t)bm * K, K, tid);
    stage128(Bs[0], BT + (size_t)bn * K, K, tid);
    __syncthreads();
    int cur = 0;
    for (int k0 = 0; k0 < K; k0 += 64) {
        if (k0 + 64 < K) {
            stage128(As[cur ^ 1], A + (size_t)bm * K + k0 + 64, K, tid);
            stage128(Bs[cur ^ 1], BT + (size_t)bn * K + k0 + 64, K, tid);
        }
#pragma unroll
        for (int kk = 0; kk < 2; ++kk) {
            const int kb = kk * 32 + l4 * 8;
            bf16x8 a[4], b[4];
#pragma unroll
            for (int m = 0; m < 4; ++m) a[m] = frag64(As[cur], wr + m * 16 + l15, kb);
#pragma unroll
            for (int n = 0; n < 4; ++n) b[n] = frag64(Bs[cur], wc + n * 16 + l15, kb);
#pragma unroll
            for (int m = 0; m < 4; ++m)
#pragma unroll
                for (int n = 0; n < 4; ++n)
                    acc[m][n] = __builtin_amdgcn_mfma_f32_16x16x32_bf16(a[m], b[n], acc[m][n], 0, 0, 0);
        }
        __syncthreads();
        cur ^= 1;
    }
#pragma unroll
    for (int m = 0; m < 4; ++m)
#pragma unroll
        for (int n = 0; n < 4; ++n)
#pragma unroll
            for (int r = 0; r < 4; ++r) {
                const size_t off = (size_t)(bm + wr + m * 16 + l4 * 4 + r) * N + bn + wc + n * 16 + l15;
                if (MODE == 0) Cb[off] = __float2bfloat16(acc[m][n][r]);
                else Cf[off] = acc[m][n][r];
            }
}

// ------------------- barrier-free direct-global attention -------------------
// 1 wave / block, 32 q-rows / wave. K,V,Q read directly from global (16B/lane
// MFMA fragments, L2-resident). Only P lives in LDS (per-wave 4KB). No syncs.
__global__ __launch_bounds__(64) void attn_direct(const bf16g* __restrict__ qkv,
                                                  const bf16g* __restrict__ vlinT,
                                                  const bf16g* __restrict__ vwT,
                                                  const float* __restrict__ bias,
                                                  bf16g* __restrict__ att) {
    __shared__ char P[4096];   // [32 rows][128B], XOR-swizzled 16B chunks
    const int bid = blockIdx.x;
    const int h = bid & 15;
    const int branch = (bid >> 4) & 1;
    const int t6 = bid >> 5;                     // 0..63
    const int qw = (t6 & 1) ? (63 - (t6 >> 1)) : (t6 >> 1);  // heavy/light interleave
    const int qbase = qw * 32;
    const int lane = threadIdx.x;
    const int l15 = lane & 15, l4 = lane >> 4;

    bf16x8 vones;
#pragma unroll
    for (int i = 0; i < 8; ++i) vones[i] = (__bf16)1.0f;
    const f32x4 zero4 = {0.f, 0.f, 0.f, 0.f};
    f32x4 acc[2][4], accl[2];
#pragma unroll
    for (int rb = 0; rb < 2; ++rb) {
        accl[rb] = zero4;
#pragma unroll
        for (int n = 0; n < 4; ++n) acc[rb][n] = zero4;
    }

    if (branch == 0) {
        // ================= win branch =================
        const bf16g* Qb = qkv + (size_t)qbase * QS + 1536 + h * 64;
        const bf16g* Kb = qkv + 2560 + h * 64;
        const bf16g* Vb = vwT + (size_t)(h * 64) * SEQ;
        bf16x8 aq[2][2];
#pragma unroll
        for (int rb = 0; rb < 2; ++rb)
#pragma unroll
            for (int kk = 0; kk < 2; ++kk)
                aq[rb][kk] = *(const bf16x8*)(Qb + (size_t)(rb * 16 + l15) * QS + kk * 32 + l4 * 8);

        const int ktEnd = min(31, (qbase + 286) >> 6);
        const int maskStart = (qbase + 256) >> 6;

        auto loadK = [&](bf16x8 (&KF)[2][4], int kt) {
#pragma unroll
            for (int kk = 0; kk < 2; ++kk)
#pragma unroll
                for (int n = 0; n < 4; ++n)
                    KF[kk][n] = *(const bf16x8*)(Kb + (size_t)(kt * 64 + n * 16 + l15) * QS + kk * 32 + l4 * 8);
        };

        auto compute = [&](int kt, const bf16x8 (&KF)[2][4]) {
            bf16x8 vv[2][4];
#pragma unroll
            for (int kk = 0; kk < 2; ++kk)
#pragma unroll
                for (int n = 0; n < 4; ++n)
                    vv[kk][n] = *(const bf16x8*)(Vb + (size_t)(n * 16 + l15) * SEQ + kt * 64 + kk * 32 + l4 * 8);
            const bool needMask = (kt >= maskStart);
#pragma unroll
            for (int rb = 0; rb < 2; ++rb) {
                f32x4 s[4];
#pragma unroll
                for (int n = 0; n < 4; ++n) {
                    f32x4 t0 = __builtin_amdgcn_mfma_f32_16x16x32_bf16(aq[rb][0], KF[0][n], zero4, 0, 0, 0);
                    s[n] = __builtin_amdgcn_mfma_f32_16x16x32_bf16(aq[rb][1], KF[1][n], t0, 0, 0, 0);
                }
                const int sgB = qbase + rb * 16 + l4 * 4;
#pragma unroll
                for (int n = 0; n < 4; ++n) {
                    const int tg = kt * 64 + n * 16 + l15;
                    const float ab = bias[tg] - 3.0f;
#pragma unroll
                    for (int r = 0; r < 4; ++r) {
                        float sc = s[n][r] * 0.125f + ab;
                        if (needMask && tg > sgB + r + 255) sc = -1e30f;
                        const float p = __expf(sc);
                        const int pr = rb * 16 + l4 * 4 + r;
                        const int pc = n * 16 + l15;
                        const int ch = pc >> 3;
                        *(bf16g*)(P + pr * 128 + ((ch ^ (pr & 7)) << 4) + (pc & 7) * 2) =
                            __float2bfloat16(p);
                    }
                }
            }
#pragma unroll
            for (int rb = 0; rb < 2; ++rb)
#pragma unroll
                for (int kk = 0; kk < 2; ++kk) {
                    bf16x8 pa = frag64(P, rb * 16 + l15, kk * 32 + l4 * 8);
#pragma unroll
                    for (int n = 0; n < 4; ++n)
                        acc[rb][n] = __builtin_amdgcn_mfma_f32_16x16x32_bf16(pa, vv[kk][n], acc[rb][n], 0, 0, 0);
                    accl[rb] = __builtin_amdgcn_mfma_f32_16x16x32_bf16(pa, vones, accl[rb], 0, 0, 0);
                }
        };

        bf16x8 kA[2][4], kB[2][4];
        loadK(kA, 0);
        for (int kt = 0; kt <= ktEnd; kt += 2) {
            if (kt + 1 <= ktEnd) loadK(kB, kt + 1);
            compute(kt, kA);
            if (kt + 1 <= ktEnd) {
                if (kt + 2 <= ktEnd) loadK(kA, kt + 2);
                compute(kt + 1, kB);
            }
        }
#pragma unroll
        for (int rb = 0; rb < 2; ++rb)
#pragma unroll
            for (int n = 0; n < 4; ++n)
#pragma unroll
                for (int r = 0; r < 4; ++r) {
                    const int sg = qbase + rb * 16 + l4 * 4 + r;
                    att[(size_t)sg * 2048 + 1024 + h * 64 + n * 16 + l15] =
                        __float2bfloat16(acc[rb][n][r] / accl[rb][r]);
                }
    } else {
        // ================= lin branch =================
        const bf16g* Qb = qkv + (size_t)qbase * QS + h * FDIM;
        const bf16g* Kb = qkv + 256 + h * FDIM;
        const bf16g* Vb = vlinT + (size_t)(h * 64) * SEQ;
        const bf16x8 zf = {};
        bf16x8 aq[2];
#pragma unroll
        for (int rb = 0; rb < 2; ++rb)
            aq[rb] = (l4 < 2) ? *(const bf16x8*)(Qb + (size_t)(rb * 16 + l15) * QS + l4 * 8) : zf;

        const int ktEnd = (qbase + 31) >> 6;

        auto loadK = [&](bf16x8 (&KF)[4], int kt) {
#pragma unroll
            for (int n = 0; n < 4; ++n)
                KF[n] = (l4 < 2) ? *(const bf16x8*)(Kb + (size_t)(kt * 64 + n * 16 + l15) * QS + l4 * 8) : zf;
        };

        auto compute = [&](int kt, const bf16x8 (&KF)[4]) {
            bf16x8 vv[2][4];
#pragma unroll
            for (int kk = 0; kk < 2; ++kk)
#pragma unroll
                for (int n = 0; n < 4; ++n)
                    vv[kk][n] = *(const bf16x8*)(Vb + (size_t)(n * 16 + l15) * SEQ + kt * 64 + kk * 32 + l4 * 8);
            const bool needMask = (kt == ktEnd);
#pragma unroll
            for (int rb = 0; rb < 2; ++rb) {
                f32x4 s[4];
#pragma unroll
                for (int n = 0; n < 4; ++n)
                    s[n] = __builtin_amdgcn_mfma_f32_16x16x32_bf16(aq[rb], KF[n], zero4, 0, 0, 0);
                const int sgB = qbase + rb * 16 + l4 * 4;
#pragma unroll
                for (int n = 0; n < 4; ++n) {
                    const int tg = kt * 64 + n * 16 + l15;
#pragma unroll
                    for (int r = 0; r < 4; ++r) {
                        const float d = s[n][r];
                        float sc = fmaf(d, fmaf(d, 1.f / 32.f, 0.25f), 1.f);
                        if (needMask && tg > sgB + r) sc = 0.f;
                        const int pr = rb * 16 + l4 * 4 + r;
                        const int pc = n * 16 + l15;
                        const int ch = pc >> 3;
                        *(bf16g*)(P + pr * 128 + ((ch ^ (pr & 7)) << 4) + (pc & 7) * 2) =
                            __float2bfloat16(sc);
                    }
                }
            }
#pragma unroll
            for (int rb = 0; rb < 2; ++rb)
#pragma unroll
                for (int kk = 0; kk < 2; ++kk) {
                    bf16x8 pa = frag64(P, rb * 16 + l15, kk * 32 + l4 * 8);
#pragma unroll
                    for (int n = 0; n < 4; ++n)
                        acc[rb][n] = __builtin_amdgcn_mfma_f32_16x16x32_bf16(pa, vv[kk][n], acc[rb][n], 0, 0, 0);
                    accl[rb] = __builtin_amdgcn_mfma_f32_16x16x32_bf16(pa, vones, accl[rb], 0, 0, 0);
                }
        };

        bf16x8 kA[4], kB[4];
        loadK(kA, 0);
        for (int kt = 0; kt <= ktEnd; kt += 2) {
            if (kt + 1 <= ktEnd) loadK(kB, kt + 1);
            compute(kt, kA);
            if (kt + 1 <= ktEnd) {
                if (kt + 2 <= ktEnd) loadK(kA, kt + 2);
                compute(kt + 1, kB);
            }
        }
#pragma unroll
        for (int rb = 0; rb < 2; ++rb)
#pragma unroll
            for (int n = 0; n < 4; ++n)
#pragma unroll
                for (int r = 0; r < 4; ++r) {
                    const int sg = qbase + rb * 16 + l4 * 4 + r;
                    att[(size_t)sg * 2048 + h * 64 + n * 16 + l15] =
                        __float2bfloat16(acc[rb][n][r] / (accl[rb][r] + 1e-9f));
                }
    }
}

// ------------------- host -------------------
extern "C" void kernel_launch(void* const* d_in, const int* in_sizes, int n_in,
                              void* d_out, int out_size, void* d_ws, size_t ws_size,
                              hipStream_t stream) {
    const float* h      = (const float*)d_in[0];
    const int*   amask  = (const int*)d_in[1];
    const float* lin_Wq = (const float*)d_in[2];
    const float* lin_Wk = (const float*)d_in[3];
    const float* lin_Wv = (const float*)d_in[4];
    const float* lin_Wo = (const float*)d_in[5];
    const float* win_Wq = (const float*)d_in[6];
    const float* win_Wk = (const float*)d_in[7];
    const float* win_Wv = (const float*)d_in[8];
    const float* win_Wo = (const float*)d_in[9];
    float* out = (float*)d_out;

    char* p = (char*)d_ws;
    bf16g* h_b   = (bf16g*)p; p += (size_t)SEQ * DIM * 2;
    bf16g* BT    = (bf16g*)p; p += (size_t)QS * DIM * 2;     // fused [4608][1024]
    bf16g* WoT   = (bf16g*)p; p += (size_t)DIM * 2048 * 2;
    bf16g* qkv   = (bf16g*)p; p += (size_t)SEQ * QS * 2;     // fused [2048][4608]
    bf16g* vlinT = (bf16g*)p; p += (size_t)DIM * SEQ * 2;
    bf16g* vwT   = (bf16g*)p; p += (size_t)DIM * SEQ * 2;
    bf16g* att   = (bf16g*)p; p += (size_t)SEQ * 2048 * 2;
    float* bias  = (float*)p; p += (size_t)SEQ * 4;

    const dim3 blk(256);
    convert_h<<<dim3(SEQ * DIM / 8 / 256), blk, 0, stream>>>(h, h_b, amask, bias);

    TP8 jobs;
    jobs.src[0] = lin_Wq; jobs.dst[0] = BT;                      jobs.C[0] = 256;  jobs.os[0] = DIM;
    jobs.src[1] = lin_Wk; jobs.dst[1] = BT + (size_t)256 * DIM;  jobs.C[1] = 256;  jobs.os[1] = DIM;
    jobs.src[2] = lin_Wv; jobs.dst[2] = BT + (size_t)512 * DIM;  jobs.C[2] = 1024; jobs.os[2] = DIM;
    jobs.src[3] = win_Wq; jobs.dst[3] = BT + (size_t)1536 * DIM; jobs.C[3] = 1024; jobs.os[3] = DIM;
    jobs.src[4] = win_Wk; jobs.dst[4] = BT + (size_t)2560 * DIM; jobs.C[4] = 1024; jobs.os[4] = DIM;
    jobs.src[5] = win_Wv; jobs.dst[5] = BT + (size_t)3584 * DIM; jobs.C[5] = 1024; jobs.os[5] = DIM;
    jobs.src[6] = lin_Wo; jobs.dst[6] = WoT;                     jobs.C[6] = 1024; jobs.os[6] = 2048;
    jobs.src[7] = win_Wo; jobs.dst[7] = WoT + 1024;              jobs.C[7] = 1024; jobs.os[7] = 2048;
    transpose8<<<dim3(32, 32, 8), blk, 0, stream>>>(jobs);

    // fused QKV projection GEMM: [2048][1024] @ [4608][1024]^T
    gemm_bf16<0><<<dim3(QS / 128, SEQ / 128), blk, 0, stream>>>(h_b, BT, nullptr, qkv, SEQ, QS, DIM);

    transposeV<<<dim3(32, 64, 2), blk, 0, stream>>>(qkv, vlinT, vwT);

    attn_direct<<<dim3(2048), dim3(64), 0, stream>>>(qkv, vlinT, vwT, bias, att);

    gemm_bf16<1><<<dim3(DIM / 128, SEQ / 128), blk, 0, stream>>>(att, WoT, out, nullptr, SEQ, DIM, 2048);
}

// Round 9
// 138.075 us; speedup vs baseline: 1.4323x; 1.4323x over previous
//
#include <hip/hip_runtime.h>
#include <hip/hip_bf16.h>
#include <math.h>

#define SEQ 2048
#define DIM 1024
#define NH 16
#define FDIM 16
#define QKS 2560   // q/k buffer row stride: linQ@0 linK@256 winQ@512 winK@1536

typedef __bf16 bf16x8 __attribute__((ext_vector_type(8)));
typedef float f32x4 __attribute__((ext_vector_type(4)));
typedef __hip_bfloat16 bf16g;

__device__ __forceinline__ void gld16(const void* g, void* l) {
    __builtin_amdgcn_global_load_lds((const __attribute__((address_space(1))) void*)g,
                                     (__attribute__((address_space(3))) void*)l, 16, 0, 0);
}

// ---- 256-thread stager (GEMM): 128x64 bf16 tile, 16B-chunk XOR swizzle ----
__device__ __forceinline__ void stage128(char* lds, const bf16g* src, int stride, int tid) {
#pragma unroll
    for (int c = 0; c < 4; ++c) {
        const int idx = ((tid >> 6) * 256) + c * 64 + (tid & 63);
        const int row = idx >> 3, gg = idx & 7;
        gld16(src + (size_t)row * stride + ((gg ^ (row & 7)) * 8), lds + idx * 16);
    }
}
// ---- 512-thread stagers (attn) ----
__device__ __forceinline__ void stage64_512(char* lds, const bf16g* src, int stride, int tid) {
    const int row = tid >> 3, gg = tid & 7;
    gld16(src + (size_t)row * stride + ((gg ^ (row & 7)) * 8), lds + tid * 16);
}
__device__ __forceinline__ void stage128_512(char* lds, const bf16g* src, int stride, int tid) {
#pragma unroll
    for (int c = 0; c < 2; ++c) {
        const int idx = c * 512 + tid;
        const int row = idx >> 3, gg = idx & 7;
        gld16(src + (size_t)row * stride + ((gg ^ (row & 7)) * 8), lds + idx * 16);
    }
}

__device__ __forceinline__ bf16x8 frag64(const char* lds, int row, int kbase) {
    const int ch = kbase >> 3;
    return *(const bf16x8*)(lds + row * 128 + ((ch ^ (row & 7)) << 4));
}
__device__ __forceinline__ bf16x8 frag32(const char* lds, int row, int kbase) {
    const int ch = kbase >> 3;
    return *(const bf16x8*)(lds + row * 64 + ((ch ^ (row & 3)) << 4));
}

// ------------------- prep kernels -------------------
__global__ __launch_bounds__(256) void convert_h(const float* __restrict__ in, bf16g* __restrict__ out,
                                                 const int* __restrict__ amask, float* __restrict__ bias) {
    const size_t base = ((size_t)blockIdx.x * 256 + threadIdx.x) * 8;
    float4 a = *(const float4*)(in + base);
    float4 b = *(const float4*)(in + base + 4);
    __attribute__((aligned(16))) bf16g t[8];
    t[0] = __float2bfloat16(a.x); t[1] = __float2bfloat16(a.y);
    t[2] = __float2bfloat16(a.z); t[3] = __float2bfloat16(a.w);
    t[4] = __float2bfloat16(b.x); t[5] = __float2bfloat16(b.y);
    t[6] = __float2bfloat16(b.z); t[7] = __float2bfloat16(b.w);
    *(uint4*)(out + base) = *(const uint4*)t;
    const int tg = blockIdx.x * 256 + threadIdx.x;
    if (tg < SEQ) bias[tg] = (amask[tg] != 0) ? 0.f : -1e30f;
}

// 8 batched weight transposes: f32 [1024][C] -> bf16 [C][os]
struct TP8 { const float* src[8]; bf16g* dst[8]; int C[8]; int os[8]; };
__global__ __launch_bounds__(256) void transpose8(TP8 jp) {
    const int j = blockIdx.z;
    const int C = jp.C[j];
    const int bc = blockIdx.x * 32;
    if (bc >= C) return;
    __shared__ float T[32][33];
    const float* in = jp.src[j];
    bf16g* out = jp.dst[j];
    const int os = jp.os[j];
    const int tid = threadIdx.x;
    const int br = blockIdx.y * 32;
    const int r = tid >> 3, c4 = (tid & 7) * 4;
    float4 v = *(const float4*)(in + (size_t)(br + r) * C + bc + c4);
    T[r][c4 + 0] = v.x; T[r][c4 + 1] = v.y; T[r][c4 + 2] = v.z; T[r][c4 + 3] = v.w;
    __syncthreads();
    const int c = tid >> 3, r4 = (tid & 7) * 4;
    __attribute__((aligned(8))) bf16g o[4];
#pragma unroll
    for (int i = 0; i < 4; ++i) o[i] = __float2bfloat16(T[r4 + i][c]);
    *(ushort4*)(out + (size_t)(bc + c) * os + br + r4) = *(const ushort4*)o;
}

// ------------------- bf16 MFMA GEMM, 2-phase pipelined -------------------
template <int MODE>
__global__ __launch_bounds__(256) void gemm_bf16(const bf16g* __restrict__ A,
                                                 const bf16g* __restrict__ BT,
                                                 float* __restrict__ Cf, bf16g* __restrict__ Cb,
                                                 int M, int N, int K) {
    __shared__ char As[2][16384];
    __shared__ char Bs[2][16384];
    const int tid = threadIdx.x, lane = tid & 63, w = tid >> 6;
    const int wr = (w >> 1) * 64, wc = (w & 1) * 64;
    const int bm = blockIdx.y * 128, bn = blockIdx.x * 128;
    const int l15 = lane & 15, l4 = lane >> 4;
    f32x4 z = {0.f, 0.f, 0.f, 0.f};
    f32x4 acc[4][4];
#pragma unroll
    for (int m = 0; m < 4; ++m)
#pragma unroll
        for (int n = 0; n < 4; ++n) acc[m][n] = z;

    stage128(As[0], A + (size_t)bm * K, K, tid);
    stage128(Bs[0], BT + (size_t)bn * K, K, tid);
    __syncthreads();
    int cur = 0;
    for (int k0 = 0; k0 < K; k0 += 64) {
        if (k0 + 64 < K) {
            stage128(As[cur ^ 1], A + (size_t)bm * K + k0 + 64, K, tid);
            stage128(Bs[cur ^ 1], BT + (size_t)bn * K + k0 + 64, K, tid);
        }
#pragma unroll
        for (int kk = 0; kk < 2; ++kk) {
            const int kb = kk * 32 + l4 * 8;
            bf16x8 a[4], b[4];
#pragma unroll
            for (int m = 0; m < 4; ++m) a[m] = frag64(As[cur], wr + m * 16 + l15, kb);
#pragma unroll
            for (int n = 0; n < 4; ++n) b[n] = frag64(Bs[cur], wc + n * 16 + l15, kb);
#pragma unroll
            for (int m = 0; m < 4; ++m)
#pragma unroll
                for (int n = 0; n < 4; ++n)
                    acc[m][n] = __builtin_amdgcn_mfma_f32_16x16x32_bf16(a[m], b[n], acc[m][n], 0, 0, 0);
        }
        __syncthreads();
        cur ^= 1;
    }
#pragma unroll
    for (int m = 0; m < 4; ++m)
#pragma unroll
        for (int n = 0; n < 4; ++n)
#pragma unroll
            for (int r = 0; r < 4; ++r) {
                const size_t off = (size_t)(bm + wr + m * 16 + l4 * 4 + r) * N + bn + wc + n * 16 + l15;
                if (MODE == 0) Cb[off] = __float2bfloat16(acc[m][n][r]);
                else Cf[off] = acc[m][n][r];
            }
}

// ------------------- fused attention: 8 waves, 128 q-rows/block -------------
// LDS map (64KB): win: Q[128][64]@0(16K), K dbuf @16384+cur*8192, V dbuf @32768+cur*8192
//                 lin: Q[128][32]@0(8K),  K dbuf @16384+cur*4096, V dbuf @32768+cur*8192
//                 P: @49152 + w*2048 (16K)
__global__ __launch_bounds__(512) void attn_fused(const bf16g* __restrict__ qk,
                                                  const bf16g* __restrict__ vT,
                                                  const float* __restrict__ bias,
                                                  bf16g* __restrict__ att) {
    __shared__ char L[65536];
    const int tid = threadIdx.x, lane = tid & 63, w = tid >> 6;
    const int bid = blockIdx.x;
    const int branch = bid & 1;
    const int rest = bid >> 1;
    const int h = rest & 15;
    const int Qt = 15 - (rest >> 4);   // heavy-first
    const int l15 = lane & 15, l4 = lane >> 4;
    char* Pw = L + 49152 + w * 2048;

    bf16x8 vones;
#pragma unroll
    for (int i = 0; i < 8; ++i) vones[i] = (__bf16)1.0f;
    const f32x4 zero4 = {0.f, 0.f, 0.f, 0.f};
    f32x4 acc[4], accl = zero4;
#pragma unroll
    for (int n = 0; n < 4; ++n) acc[n] = zero4;
    const int qrow = w * 16 + l15;
    const int sgBase = Qt * 128 + w * 16 + l4 * 4;

    if (branch == 0) {
        // ---------------- win branch ----------------
        const bf16g* Qp = qk + (size_t)(Qt * 128) * QKS + 512 + h * 64;
        const bf16g* Kp = qk + 1536 + h * 64;
        const bf16g* Vp = vT + (size_t)(1024 + h * 64) * SEQ;

        stage128_512(L, Qp, QKS, tid);
        stage64_512(L + 16384, Kp, QKS, tid);
        stage64_512(L + 32768, Vp, SEQ, tid);
        __syncthreads();
        const bf16x8 aq0 = frag64(L, qrow, l4 * 8);
        const bf16x8 aq1 = frag64(L, qrow, 32 + l4 * 8);
        const int ktEnd = min(31, 2 * Qt + 5);
        int cur = 0;
        for (int kt = 0; kt <= ktEnd; ++kt) {
            const int kOff = 16384 + cur * 8192;
            const int vOff = 32768 + cur * 8192;
            if (kt < ktEnd) {
                stage64_512(L + (16384 + (cur ^ 1) * 8192), Kp + (size_t)((kt + 1) * 64) * QKS, QKS, tid);
                stage64_512(L + (32768 + (cur ^ 1) * 8192), Vp + (kt + 1) * 64, SEQ, tid);
            }
            f32x4 s[4];
            __builtin_amdgcn_s_setprio(1);
#pragma unroll
            for (int n = 0; n < 4; ++n) {
                f32x4 t = zero4;
                t = __builtin_amdgcn_mfma_f32_16x16x32_bf16(aq0, frag64(L + kOff, n * 16 + l15, l4 * 8), t, 0, 0, 0);
                t = __builtin_amdgcn_mfma_f32_16x16x32_bf16(aq1, frag64(L + kOff, n * 16 + l15, 32 + l4 * 8), t, 0, 0, 0);
                s[n] = t;
            }
            __builtin_amdgcn_s_setprio(0);
            const bool needMask = (kt >= 2 * Qt + 4);
#pragma unroll
            for (int n = 0; n < 4; ++n) {
                const float ab = bias[kt * 64 + n * 16 + l15] - 3.0f;
#pragma unroll
                for (int r = 0; r < 4; ++r) {
                    float sc = s[n][r] * 0.125f + ab;
                    if (needMask) {
                        const int tg = kt * 64 + n * 16 + l15;
                        if (tg > sgBase + r + 255) sc = -1e30f;
                    }
                    const float p = __expf(sc);
                    const int prow = l4 * 4 + r;
                    const int pcol = n * 16 + l15;
                    const int ch = pcol >> 3;
                    *(bf16g*)(Pw + prow * 128 + ((ch ^ (prow & 7)) << 4) + (pcol & 7) * 2) =
                        __float2bfloat16(p);
                }
            }
            __builtin_amdgcn_s_setprio(1);
#pragma unroll
            for (int kk = 0; kk < 2; ++kk) {
                bf16x8 pa = frag64(Pw, l15, kk * 32 + l4 * 8);
#pragma unroll
                for (int n = 0; n < 4; ++n)
                    acc[n] = __builtin_amdgcn_mfma_f32_16x16x32_bf16(
                        pa, frag64(L + vOff, n * 16 + l15, kk * 32 + l4 * 8), acc[n], 0, 0, 0);
                accl = __builtin_amdgcn_mfma_f32_16x16x32_bf16(pa, vones, accl, 0, 0, 0);
            }
            __builtin_amdgcn_s_setprio(0);
            __syncthreads();
            cur ^= 1;
        }
#pragma unroll
        for (int n = 0; n < 4; ++n)
#pragma unroll
            for (int r = 0; r < 4; ++r) {
                const int sg = sgBase + r;
                att[(size_t)sg * 2048 + 1024 + h * 64 + n * 16 + l15] =
                    __float2bfloat16(acc[n][r] / accl[r]);
            }
    } else {
        // ---------------- lin branch ----------------
        const bf16g* Qp = qk + (size_t)(Qt * 128) * QKS + h * FDIM;
        const bf16g* Kp = qk + 256 + h * FDIM;
        const bf16g* Vp = vT + (size_t)(h * 64) * SEQ;

        const uint4 z4 = {0u, 0u, 0u, 0u};
        {   // Q [128][32] zero-padded
            const int row = tid >> 2, gp = tid & 3, g = gp ^ (row & 3);
            uint4 qv = (g < 2) ? *(const uint4*)(Qp + (size_t)row * QKS + g * 8) : z4;
            *(uint4*)(L + row * 64 + gp * 16) = qv;
        }
        if (tid < 256) {   // K [64][32]
            const int row = tid >> 2, gp = tid & 3, g = gp ^ (row & 3);
            uint4 kv = (g < 2) ? *(const uint4*)(Kp + (size_t)row * QKS + g * 8) : z4;
            *(uint4*)(L + 16384 + row * 64 + gp * 16) = kv;
        }
        stage64_512(L + 32768, Vp, SEQ, tid);
        __syncthreads();
        const bf16x8 aq = frag32(L, qrow, l4 * 8);
        const int ktEnd = 2 * Qt + 1;
        int cur = 0;
        for (int kt = 0; kt <= ktEnd; ++kt) {
            const int kOff = 16384 + cur * 4096;
            const int vOff = 32768 + cur * 8192;
            uint4 knext = z4;
            const int row = tid >> 2, gp = tid & 3, g = gp ^ (row & 3);
            if (kt < ktEnd) {
                if (tid < 256 && g < 2)
                    knext = *(const uint4*)(Kp + (size_t)((kt + 1) * 64 + row) * QKS + g * 8);
                stage64_512(L + (32768 + (cur ^ 1) * 8192), Vp + (kt + 1) * 64, SEQ, tid);
            }
            f32x4 s[4];
            __builtin_amdgcn_s_setprio(1);
#pragma unroll
            for (int n = 0; n < 4; ++n)
                s[n] = __builtin_amdgcn_mfma_f32_16x16x32_bf16(aq, frag32(L + kOff, n * 16 + l15, l4 * 8), zero4, 0, 0, 0);
            __builtin_amdgcn_s_setprio(0);
            const bool needMask = (kt >= 2 * Qt);
#pragma unroll
            for (int n = 0; n < 4; ++n)
#pragma unroll
                for (int r = 0; r < 4; ++r) {
                    const float d = s[n][r];
                    float sc = 1.f + 0.25f * d + d * d * (1.f / 32.f);
                    if (needMask) {
                        const int tg = kt * 64 + n * 16 + l15;
                        if (tg > sgBase + r) sc = 0.f;
                    }
                    const int prow = l4 * 4 + r;
                    const int pcol = n * 16 + l15;
                    const int ch = pcol >> 3;
                    *(bf16g*)(Pw + prow * 128 + ((ch ^ (prow & 7)) << 4) + (pcol & 7) * 2) =
                        __float2bfloat16(sc);
                }
            __builtin_amdgcn_s_setprio(1);
#pragma unroll
            for (int kk = 0; kk < 2; ++kk) {
                bf16x8 pa = frag64(Pw, l15, kk * 32 + l4 * 8);
#pragma unroll
                for (int n = 0; n < 4; ++n)
                    acc[n] = __builtin_amdgcn_mfma_f32_16x16x32_bf16(
                        pa, frag64(L + vOff, n * 16 + l15, kk * 32 + l4 * 8), acc[n], 0, 0, 0);
                accl = __builtin_amdgcn_mfma_f32_16x16x32_bf16(pa, vones, accl, 0, 0, 0);
            }
            __builtin_amdgcn_s_setprio(0);
            if (kt < ktEnd && tid < 256)
                *(uint4*)(L + (16384 + (cur ^ 1) * 4096) + row * 64 + gp * 16) = knext;
            __syncthreads();
            cur ^= 1;
        }
#pragma unroll
        for (int n = 0; n < 4; ++n)
#pragma unroll
            for (int r = 0; r < 4; ++r) {
                const int sg = sgBase + r;
                att[(size_t)sg * 2048 + h * 64 + n * 16 + l15] =
                    __float2bfloat16(acc[n][r] / (accl[r] + 1e-9f));
            }
    }
}

// ------------------- host -------------------
extern "C" void kernel_launch(void* const* d_in, const int* in_sizes, int n_in,
                              void* d_out, int out_size, void* d_ws, size_t ws_size,
                              hipStream_t stream) {
    const float* h      = (const float*)d_in[0];
    const int*   amask  = (const int*)d_in[1];
    const float* lin_Wq = (const float*)d_in[2];
    const float* lin_Wk = (const float*)d_in[3];
    const float* lin_Wv = (const float*)d_in[4];
    const float* lin_Wo = (const float*)d_in[5];
    const float* win_Wq = (const float*)d_in[6];
    const float* win_Wk = (const float*)d_in[7];
    const float* win_Wv = (const float*)d_in[8];
    const float* win_Wo = (const float*)d_in[9];
    float* out = (float*)d_out;

    char* p = (char*)d_ws;
    bf16g* h_b   = (bf16g*)p; p += (size_t)SEQ * DIM * 2;
    bf16g* BTqk  = (bf16g*)p; p += (size_t)QKS * DIM * 2;    // [2560][1024]
    bf16g* WvT   = (bf16g*)p; p += (size_t)2048 * DIM * 2;   // [linV^T; winV^T]
    bf16g* WoT   = (bf16g*)p; p += (size_t)DIM * 2048 * 2;
    bf16g* qkb   = (bf16g*)p; p += (size_t)SEQ * QKS * 2;    // [2048][2560]
    bf16g* vT    = (bf16g*)p; p += (size_t)2048 * SEQ * 2;   // [2048][2048]
    bf16g* att   = (bf16g*)p; p += (size_t)SEQ * 2048 * 2;
    float* bias  = (float*)p; p += (size_t)SEQ * 4;

    const dim3 blk(256);
    convert_h<<<dim3(SEQ * DIM / 8 / 256), blk, 0, stream>>>(h, h_b, amask, bias);

    TP8 jobs;
    jobs.src[0] = lin_Wq; jobs.dst[0] = BTqk;                      jobs.C[0] = 256;  jobs.os[0] = DIM;
    jobs.src[1] = lin_Wk; jobs.dst[1] = BTqk + (size_t)256 * DIM;  jobs.C[1] = 256;  jobs.os[1] = DIM;
    jobs.src[2] = win_Wq; jobs.dst[2] = BTqk + (size_t)512 * DIM;  jobs.C[2] = 1024; jobs.os[2] = DIM;
    jobs.src[3] = win_Wk; jobs.dst[3] = BTqk + (size_t)1536 * DIM; jobs.C[3] = 1024; jobs.os[3] = DIM;
    jobs.src[4] = lin_Wv; jobs.dst[4] = WvT;                       jobs.C[4] = 1024; jobs.os[4] = DIM;
    jobs.src[5] = win_Wv; jobs.dst[5] = WvT + (size_t)1024 * DIM;  jobs.C[5] = 1024; jobs.os[5] = DIM;
    jobs.src[6] = lin_Wo; jobs.dst[6] = WoT;                       jobs.C[6] = 1024; jobs.os[6] = 2048;
    jobs.src[7] = win_Wo; jobs.dst[7] = WoT + 1024;                jobs.C[7] = 1024; jobs.os[7] = 2048;
    transpose8<<<dim3(32, 32, 8), blk, 0, stream>>>(jobs);

    // Q/K projection: [2048][2560]
    gemm_bf16<0><<<dim3(QKS / 128, SEQ / 128), blk, 0, stream>>>(h_b, BTqk, nullptr, qkb, SEQ, QKS, DIM);
    // V^T produced directly: vT[2048 dims][2048 seq] = WvT_stack @ h_b^T
    gemm_bf16<0><<<dim3(SEQ / 128, 2048 / 128), blk, 0, stream>>>(WvT, h_b, nullptr, vT, 2048, SEQ, DIM);

    attn_fused<<<dim3(2 * SEQ / 128 * NH), dim3(512), 0, stream>>>(qkb, vT, bias, att);

    gemm_bf16<1><<<dim3(DIM / 128, SEQ / 128), blk, 0, stream>>>(att, WoT, out, nullptr, SEQ, DIM, 2048);
}